// Round 1
// baseline (1808.486 us; speedup 1.0000x reference)
//
#include <hip/hip_runtime.h>
#include <stdint.h>

#define HDIM 1024
#define NIDX 65536
#define NSEG 8192
#define KD   1024
#define ND   1024

// producer work-queue layout
#define W_ITEMS   256                      // W fp32->bf16, 4096 floats each
#define ST_ITEMS  128                      // starts scan, 512 entries each
#define SEG_ITEMS 4096                     // 2 segments each
#define TOT_ITEMS (W_ITEMS + ST_ITEMS + SEG_ITEMS)
#define TILES_TOT 512                      // 64 m-tiles x 8 n-tiles

typedef __bf16 bf16x8 __attribute__((ext_vector_type(8)));
typedef float  f32x4  __attribute__((ext_vector_type(4)));

struct Ctrl {
  int q1;             // producer item queue
  int q2;             // gemm tile queue
  int st_done;        // completed starts items (==ST_ITEMS when ready)
  int w_done;         // completed W items (==W_ITEMS when ready)
  int pad[4];
  int chunk_done[64]; // segments completed per 128-row m-chunk (==128 when ready)
};

__device__ __forceinline__ unsigned short f2bf(float f) {
  unsigned int u = __float_as_uint(f);
  u += 0x7fffu + ((u >> 16) & 1u);   // RNE
  return (unsigned short)(u >> 16);
}

__device__ __forceinline__ void async16(const void* g, void* l) {
  __builtin_amdgcn_global_load_lds(
      (const __attribute__((address_space(1))) void*)g,
      (__attribute__((address_space(3))) void*)l,
      16, 0, 0);
}

// Fused persistent kernel: producer/consumer pipeline.
// Every block: claim a GEMM tile; while its m-chunk isn't produced, help drain
// the producer queue (W conv / starts scan / segment means). Deadlock-free
// under ANY block scheduling: a blocked consumer always makes producer
// progress; queue items are completed by their (resident, running) claimers.
__global__ void __launch_bounds__(512, 4)
fused_kernel(const float* __restrict__ hid,
             const int* __restrict__ indices,
             const int* __restrict__ seg,
             const float* __restrict__ W_dense,
             const float* __restrict__ b_dense,
             const float* __restrict__ w_proj,
             const float* __restrict__ b_proj,
             unsigned short* __restrict__ hb,
             unsigned short* __restrict__ Wb,
             int* __restrict__ starts,
             Ctrl* __restrict__ ctrl,
             float* __restrict__ out) {
  __shared__ alignas(16) unsigned short As[128 * 64];  // 16 KiB
  __shared__ alignas(16) unsigned short Bs[128 * 64];  // 16 KiB
  __shared__ int s_bcast;

  const int tid = threadIdx.x;

  bool st_ok    = false;   // this block has observed starts complete
  bool q1_empty = false;

  // claim first tile
  __syncthreads();
  if (tid == 0) s_bcast = atomicAdd(&ctrl->q2, 1);
  __syncthreads();
  int my_tile = s_bcast;

  while (my_tile < TILES_TOT) {
    const int mt = my_tile >> 3;

    // single-shot readiness poll (tid0 -> broadcast)
    __syncthreads();
    if (tid == 0) {
      int wd = __hip_atomic_load(&ctrl->w_done, __ATOMIC_ACQUIRE, __HIP_MEMORY_SCOPE_AGENT);
      int cd = __hip_atomic_load(&ctrl->chunk_done[mt], __ATOMIC_ACQUIRE, __HIP_MEMORY_SCOPE_AGENT);
      s_bcast = (wd == W_ITEMS && cd >= 128) ? 1 : 0;
    }
    __syncthreads();

    if (s_bcast) {
      // ---------------- consume: GEMM + bias + erf-GELU + proj for one tile --
      __builtin_amdgcn_fence(__ATOMIC_ACQUIRE, "agent");  // invalidate stale L2 before reading hb/Wb
      const int m0   = mt * 128;
      const int n0   = (my_tile & 7) * 128;
      const int lane = tid & 63;
      const int wave = tid >> 6;
      const int wm   = wave >> 2;
      const int wn   = wave & 3;
      const int lr   = lane & 15;
      const int quad = lane >> 4;

      f32x4 acc[4][2];
#pragma unroll
      for (int mi = 0; mi < 4; ++mi)
#pragma unroll
        for (int ni = 0; ni < 2; ++ni) {
          acc[mi][ni][0] = 0.f; acc[mi][ni][1] = 0.f;
          acc[mi][ni][2] = 0.f; acc[mi][ni][3] = 0.f;
        }

      for (int kt = 0; kt < KD / 64; ++kt) {
        const int k0 = kt * 64;
#pragma unroll
        for (int j = 0; j < 2; ++j) {
          int c   = j * 512 + wave * 64 + lane;
          int row = c >> 3, sl = c & 7;
          int kcg = sl ^ (row & 7);
          async16(hb + (size_t)(m0 + row) * KD + k0 + kcg * 8,
                  (char*)As + (j * 512 + wave * 64) * 16);
        }
#pragma unroll
        for (int j = 0; j < 2; ++j) {
          int c   = j * 512 + wave * 64 + lane;
          int row = c >> 3, sl = c & 7;
          int kcg = sl ^ (row & 7);
          async16(Wb + (size_t)(n0 + row) * KD + k0 + kcg * 8,
                  (char*)Bs + (j * 512 + wave * 64) * 16);
        }
        __syncthreads();

#pragma unroll
        for (int s = 0; s < 2; ++s) {
          bf16x8 af[4], bf_[2];
#pragma unroll
          for (int i = 0; i < 4; ++i) {
            int ra   = wm * 64 + i * 16 + lr;
            int slot = (s * 4 + quad) ^ (ra & 7);
            af[i] = *(const bf16x8*)(As + ra * 64 + slot * 8);
          }
#pragma unroll
          for (int i = 0; i < 2; ++i) {
            int rb   = wn * 32 + i * 16 + lr;
            int slot = (s * 4 + quad) ^ (rb & 7);
            bf_[i] = *(const bf16x8*)(Bs + rb * 64 + slot * 8);
          }
#pragma unroll
          for (int mi = 0; mi < 4; ++mi)
#pragma unroll
            for (int ni = 0; ni < 2; ++ni)
              acc[mi][ni] = __builtin_amdgcn_mfma_f32_16x16x32_bf16(af[mi], bf_[ni], acc[mi][ni], 0, 0, 0);
        }
        __syncthreads();
      }

#pragma unroll
      for (int mi = 0; mi < 4; ++mi) {
        float rp[4] = {0.f, 0.f, 0.f, 0.f};
#pragma unroll
        for (int ni = 0; ni < 2; ++ni) {
          int col  = n0 + wn * 32 + ni * 16 + lr;
          float bd = b_dense[col];
          float wp = w_proj[col];
#pragma unroll
          for (int r = 0; r < 4; ++r) {
            float v  = acc[mi][ni][r] + bd;
            float gl = 0.5f * v * (1.0f + erff(v * 0.70710678118654752f));
            rp[r] += gl * wp;
          }
        }
#pragma unroll
        for (int r = 0; r < 4; ++r) {
          float c = rp[r];
          c += __shfl_xor(c, 1);
          c += __shfl_xor(c, 2);
          c += __shfl_xor(c, 4);
          c += __shfl_xor(c, 8);
          if (lr == 0)
            atomicAdd(out + (m0 + wm * 64 + mi * 16 + quad * 4 + r), c);
        }
      }

      // claim next tile
      __syncthreads();
      if (tid == 0) s_bcast = atomicAdd(&ctrl->q2, 1);
      __syncthreads();
      my_tile = s_bcast;
      continue;
    }

    if (!q1_empty) {
      // ---------------- produce: claim one queue item ----------------
      __syncthreads();
      if (tid == 0) s_bcast = atomicAdd(&ctrl->q1, 1);
      __syncthreads();
      const int it = s_bcast;
      if (it >= TOT_ITEMS) { q1_empty = true; continue; }

      if (it < W_ITEMS) {
        // W fp32 -> bf16, 4096 floats per item, unit-stride
        const int base = it * 4096;
#pragma unroll
        for (int p = 0; p < 2; ++p) {
          int i = base + p * 2048 + tid * 4;
          float4 v = *(const float4*)(W_dense + i);
          ushort4 o;
          o.x = f2bf(v.x); o.y = f2bf(v.y); o.z = f2bf(v.z); o.w = f2bf(v.w);
          *(ushort4*)(Wb + i) = o;
        }
        __builtin_amdgcn_fence(__ATOMIC_RELEASE, "agent");
        __syncthreads();
        if (tid == 0)
          __hip_atomic_fetch_add(&ctrl->w_done, 1, __ATOMIC_RELEASE, __HIP_MEMORY_SCOPE_AGENT);
      } else if (it < W_ITEMS + ST_ITEMS) {
        // segment-boundary scan, 512 entries per item
        const int i    = (it - W_ITEMS) * 512 + tid;
        const int cur  = seg[i];
        const int prev = (i == 0) ? -1 : seg[i - 1];
        for (int g = prev + 1; g <= cur; ++g) starts[g] = i;
        if (i == NIDX - 1)
          for (int g = cur + 1; g <= NSEG; ++g) starts[g] = NIDX;
        __builtin_amdgcn_fence(__ATOMIC_RELEASE, "agent");
        __syncthreads();
        if (tid == 0)
          __hip_atomic_fetch_add(&ctrl->st_done, 1, __ATOMIC_RELEASE, __HIP_MEMORY_SCOPE_AGENT);
      } else {
        // segment means: 2 segments, one per 256-thread half-block
        const int z = it - (W_ITEMS + ST_ITEMS);
        if (!st_ok) {
          for (;;) {
            __syncthreads();
            if (tid == 0)
              s_bcast = (__hip_atomic_load(&ctrl->st_done, __ATOMIC_ACQUIRE,
                                           __HIP_MEMORY_SCOPE_AGENT) == ST_ITEMS) ? 1 : 0;
            __syncthreads();
            if (s_bcast) break;
            __builtin_amdgcn_s_sleep(2);
          }
          __builtin_amdgcn_fence(__ATOMIC_ACQUIRE, "agent");
          st_ok = true;
        }
        const int g     = 2 * z + (tid >> 8);
        const int t     = tid & 255;
        const int start = starts[g];
        const int end   = starts[g + 1];
        const int col   = t * 4;

        float4 a0 = make_float4(0.f, 0.f, 0.f, 0.f);
        float4 a1 = a0, a2 = a0, a3 = a0;
        int i = start;
        for (; i + 4 <= end; i += 4) {
          int r0 = indices[i];
          int r1 = indices[i + 1];
          int r2 = indices[i + 2];
          int r3 = indices[i + 3];
          float4 v0 = *(const float4*)(hid + (size_t)r0 * HDIM + col);
          float4 v1 = *(const float4*)(hid + (size_t)r1 * HDIM + col);
          float4 v2 = *(const float4*)(hid + (size_t)r2 * HDIM + col);
          float4 v3 = *(const float4*)(hid + (size_t)r3 * HDIM + col);
          a0.x += v0.x; a0.y += v0.y; a0.z += v0.z; a0.w += v0.w;
          a1.x += v1.x; a1.y += v1.y; a1.z += v1.z; a1.w += v1.w;
          a2.x += v2.x; a2.y += v2.y; a2.z += v2.z; a2.w += v2.w;
          a3.x += v3.x; a3.y += v3.y; a3.z += v3.z; a3.w += v3.w;
        }
        for (; i < end; ++i) {
          int r = indices[i];
          float4 v = *(const float4*)(hid + (size_t)r * HDIM + col);
          a0.x += v.x; a0.y += v.y; a0.z += v.z; a0.w += v.w;
        }
        a0.x += a1.x + a2.x + a3.x;
        a0.y += a1.y + a2.y + a3.y;
        a0.z += a1.z + a2.z + a3.z;
        a0.w += a1.w + a2.w + a3.w;

        const float inv = 1.0f / fmaxf((float)(end - start), 1.0f);
        ushort4 o;
        o.x = f2bf(a0.x * inv); o.y = f2bf(a0.y * inv);
        o.z = f2bf(a0.z * inv); o.w = f2bf(a0.w * inv);
        *(ushort4*)(hb + (size_t)g * HDIM + col) = o;
        if (t == 0) out[g] = b_proj[0];

        __builtin_amdgcn_fence(__ATOMIC_RELEASE, "agent");
        __syncthreads();
        if (tid == 0)
          __hip_atomic_fetch_add(&ctrl->chunk_done[z >> 6], 2, __ATOMIC_RELEASE,
                                 __HIP_MEMORY_SCOPE_AGENT);
      }
      continue;
    }

    // queue drained, tile not ready yet: in-flight producers will finish
    __builtin_amdgcn_s_sleep(8);
  }
}

extern "C" void kernel_launch(void* const* d_in, const int* in_sizes, int n_in,
                              void* d_out, int out_size, void* d_ws, size_t ws_size,
                              hipStream_t stream) {
  const float* hid     = (const float*)d_in[0];
  const int*   indices = (const int*)d_in[1];
  const int*   seg     = (const int*)d_in[2];
  const float* W_dense = (const float*)d_in[3];
  const float* b_dense = (const float*)d_in[4];
  const float* W_proj  = (const float*)d_in[5];
  const float* b_proj  = (const float*)d_in[6];
  float* out = (float*)d_out;

  // ws: h_bf16 [NSEG*KD] (16 MiB) | W_bf16 [ND*KD] (2 MiB) | starts[NSEG+1] | Ctrl
  unsigned short* hb = (unsigned short*)d_ws;
  unsigned short* Wb = (unsigned short*)((char*)d_ws + (size_t)NSEG * KD * 2);
  int* starts = (int*)((char*)d_ws + (size_t)NSEG * KD * 2 + (size_t)ND * KD * 2);
  size_t off = (size_t)NSEG * KD * 2 + (size_t)ND * KD * 2 + (size_t)(NSEG + 1) * 4;
  off = (off + 255) & ~(size_t)255;
  Ctrl* ctrl = (Ctrl*)((char*)d_ws + off);

  hipMemsetAsync(ctrl, 0, sizeof(Ctrl), stream);
  fused_kernel<<<dim3(TILES_TOT), 512, 0, stream>>>(
      hid, indices, seg, W_dense, b_dense, W_proj, b_proj, hb, Wb, starts, ctrl, out);
}

// Round 2
// 233.844 us; speedup vs baseline: 7.7337x; 7.7337x over previous
//
#include <hip/hip_runtime.h>
#include <stdint.h>

#define BH   (8 * 4096)
#define HDIM 1024
#define NIDX 65536
#define NSEG 8192
#define KD   1024
#define ND   1024

typedef __bf16 bf16x8 __attribute__((ext_vector_type(8)));
typedef float  f32x4  __attribute__((ext_vector_type(4)));

__device__ __forceinline__ unsigned short f2bf(float f) {
  unsigned int u = __float_as_uint(f);
  u += 0x7fffu + ((u >> 16) & 1u);   // RNE
  return (unsigned short)(u >> 16);
}

__device__ __forceinline__ void async16(const void* g, void* l) {
  __builtin_amdgcn_global_load_lds(
      (const __attribute__((address_space(1))) void*)g,
      (__attribute__((address_space(3))) void*)l,
      16, 0, 0);
}

// ---------------- Kernel 0: fused W conv (bf16) + segment boundaries ----------------
__global__ void prep_kernel(const float* __restrict__ W, unsigned short* __restrict__ Wb,
                            const int* __restrict__ seg, int* __restrict__ starts) {
  if (blockIdx.x < 1024) {
    int i = (blockIdx.x * 256 + threadIdx.x) * 4;
    float4 v = *(const float4*)(W + i);
    ushort4 o;
    o.x = f2bf(v.x); o.y = f2bf(v.y); o.z = f2bf(v.z); o.w = f2bf(v.w);
    *(ushort4*)(Wb + i) = o;
  } else {
    int i = (blockIdx.x - 1024) * 256 + threadIdx.x;
    if (i > NIDX) return;
    int prev = (i == 0) ? -1 : seg[i - 1];
    int cur  = (i == NIDX) ? NSEG : seg[i];
    for (int g = prev + 1; g <= cur; ++g) starts[g] = i;
  }
}

// ---------------- Kernel 1: segment mean -> h (bf16), init out ----------------
__global__ void segmean_kernel(const float* __restrict__ hid,
                               const int* __restrict__ indices,
                               const int* __restrict__ starts,
                               unsigned short* __restrict__ hb,
                               float* __restrict__ out,
                               const float* __restrict__ b_proj) {
  const int g = blockIdx.x;
  const int t = threadIdx.x;
  const int start = starts[g];
  const int end   = starts[g + 1];
  const int col   = t * 4;

  float4 a0 = make_float4(0.f, 0.f, 0.f, 0.f);
  float4 a1 = a0, a2 = a0, a3 = a0;

  int i = start;
  for (; i + 4 <= end; i += 4) {
    int r0 = indices[i];
    int r1 = indices[i + 1];
    int r2 = indices[i + 2];
    int r3 = indices[i + 3];
    float4 v0 = *(const float4*)(hid + (size_t)r0 * HDIM + col);
    float4 v1 = *(const float4*)(hid + (size_t)r1 * HDIM + col);
    float4 v2 = *(const float4*)(hid + (size_t)r2 * HDIM + col);
    float4 v3 = *(const float4*)(hid + (size_t)r3 * HDIM + col);
    a0.x += v0.x; a0.y += v0.y; a0.z += v0.z; a0.w += v0.w;
    a1.x += v1.x; a1.y += v1.y; a1.z += v1.z; a1.w += v1.w;
    a2.x += v2.x; a2.y += v2.y; a2.z += v2.z; a2.w += v2.w;
    a3.x += v3.x; a3.y += v3.y; a3.z += v3.z; a3.w += v3.w;
  }
  for (; i < end; ++i) {
    int r = indices[i];
    float4 v = *(const float4*)(hid + (size_t)r * HDIM + col);
    a0.x += v.x; a0.y += v.y; a0.z += v.z; a0.w += v.w;
  }
  a0.x += a1.x + a2.x + a3.x;
  a0.y += a1.y + a2.y + a3.y;
  a0.z += a1.z + a2.z + a3.z;
  a0.w += a1.w + a2.w + a3.w;

  const float inv = 1.0f / fmaxf((float)(end - start), 1.0f);
  ushort4 o;
  o.x = f2bf(a0.x * inv); o.y = f2bf(a0.y * inv);
  o.z = f2bf(a0.z * inv); o.w = f2bf(a0.w * inv);
  *(ushort4*)(hb + (size_t)g * HDIM + col) = o;

  if (t == 0) out[g] = b_proj[0];
}

// ---------------- Kernel 2: fused GEMM + bias + erf-GELU + proj ----------------
// C tile 128x128, BK=128, 512 threads = 8 waves (2m x 4n), wave tile 64x32.
// BK=128 (vs 64): halves the number of vmcnt(0)-drain + barrier events (8 K-tiles
// x 2 barriers vs 16 x 2) at identical total load bytes. LDS 64 KiB -> 2 blocks/CU,
// which the 512-block grid on 256 CUs provides anyway (all blocks co-resident).
// Grid (x = m-tile 64, y = n-tile 8): linear id = y*64+x -> XCD = x%8, so all 8
// n-blocks of an m-tile co-reside on one XCD; per-XCD L2 working set ~4 MiB.
// LDS row = 16 chunks of 16B; chunk kc stored at slot kc ^ (row&15); ds_read_b128
// across 16 rows then hits 16 distinct slots -> banks 4*(slot%8), 2-way = free.
__global__ void __launch_bounds__(512)
gemm_gelu_proj_kernel(const unsigned short* __restrict__ A,   // h  [NSEG,KD] bf16
                      const unsigned short* __restrict__ Bw,  // W  [ND,KD]  bf16
                      const float* __restrict__ b_dense,
                      const float* __restrict__ w_proj,
                      float* __restrict__ out) {
  __shared__ alignas(16) unsigned short As[128 * 128];  // 32 KiB
  __shared__ alignas(16) unsigned short Bs[128 * 128];  // 32 KiB

  const int tid  = threadIdx.x;
  const int lane = tid & 63;
  const int wave = tid >> 6;       // 0..7
  const int wm   = wave >> 2;      // 0..1 -> 64 rows
  const int wn   = wave & 3;       // 0..3 -> 32 cols
  const int m0   = blockIdx.x * 128;
  const int n0   = blockIdx.y * 128;
  const int lr   = lane & 15;
  const int quad = lane >> 4;

  f32x4 acc[4][2];
#pragma unroll
  for (int mi = 0; mi < 4; ++mi)
#pragma unroll
    for (int ni = 0; ni < 2; ++ni) {
      acc[mi][ni][0] = 0.f; acc[mi][ni][1] = 0.f;
      acc[mi][ni][2] = 0.f; acc[mi][ni][3] = 0.f;
    }

  for (int kt = 0; kt < KD / 128; ++kt) {
    const int k0 = kt * 128;
    // A tile: 128x128 bf16 = 2048 chunks of 16B; 4 per thread. Same for B.
#pragma unroll
    for (int j = 0; j < 4; ++j) {
      int c   = j * 512 + wave * 64 + lane;
      int row = c >> 4, sl = c & 15;
      int kcg = sl ^ (row & 15);
      async16(A + (size_t)(m0 + row) * KD + k0 + kcg * 8,
              (char*)As + (j * 512 + wave * 64) * 16);
    }
#pragma unroll
    for (int j = 0; j < 4; ++j) {
      int c   = j * 512 + wave * 64 + lane;
      int row = c >> 4, sl = c & 15;
      int kcg = sl ^ (row & 15);
      async16(Bw + (size_t)(n0 + row) * KD + k0 + kcg * 8,
              (char*)Bs + (j * 512 + wave * 64) * 16);
    }
    __syncthreads();

#pragma unroll
    for (int s = 0; s < 4; ++s) {           // four k-steps of 32
      bf16x8 af[4], bf_[2];
#pragma unroll
      for (int i = 0; i < 4; ++i) {
        int ra   = wm * 64 + i * 16 + lr;
        int slot = (s * 4 + quad) ^ (ra & 15);
        af[i] = *(const bf16x8*)(As + ra * 128 + slot * 8);
      }
#pragma unroll
      for (int i = 0; i < 2; ++i) {
        int rb   = wn * 32 + i * 16 + lr;
        int slot = (s * 4 + quad) ^ (rb & 15);
        bf_[i] = *(const bf16x8*)(Bs + rb * 128 + slot * 8);
      }
#pragma unroll
      for (int mi = 0; mi < 4; ++mi)
#pragma unroll
        for (int ni = 0; ni < 2; ++ni)
          acc[mi][ni] = __builtin_amdgcn_mfma_f32_16x16x32_bf16(af[mi], bf_[ni], acc[mi][ni], 0, 0, 0);
    }
    __syncthreads();
  }

  // Epilogue: bias + exact erf-GELU + w_proj; per-row partial over this wave's 32 cols
#pragma unroll
  for (int mi = 0; mi < 4; ++mi) {
    float rp[4] = {0.f, 0.f, 0.f, 0.f};
#pragma unroll
    for (int ni = 0; ni < 2; ++ni) {
      int col  = n0 + wn * 32 + ni * 16 + lr;
      float bd = b_dense[col];
      float wp = w_proj[col];
#pragma unroll
      for (int r = 0; r < 4; ++r) {
        float v  = acc[mi][ni][r] + bd;
        float gl = 0.5f * v * (1.0f + erff(v * 0.70710678118654752f));
        rp[r] += gl * wp;
      }
    }
#pragma unroll
    for (int r = 0; r < 4; ++r) {
      float c = rp[r];
      c += __shfl_xor(c, 1);
      c += __shfl_xor(c, 2);
      c += __shfl_xor(c, 4);
      c += __shfl_xor(c, 8);
      if (lr == 0)
        atomicAdd(out + (m0 + wm * 64 + mi * 16 + quad * 4 + r), c);
    }
  }
}

extern "C" void kernel_launch(void* const* d_in, const int* in_sizes, int n_in,
                              void* d_out, int out_size, void* d_ws, size_t ws_size,
                              hipStream_t stream) {
  const float* hid     = (const float*)d_in[0];
  const int*   indices = (const int*)d_in[1];
  const int*   seg     = (const int*)d_in[2];
  const float* W_dense = (const float*)d_in[3];
  const float* b_dense = (const float*)d_in[4];
  const float* W_proj  = (const float*)d_in[5];
  const float* b_proj  = (const float*)d_in[6];
  float* out = (float*)d_out;

  // ws layout: h_bf16 [NSEG*KD] (16 MiB) | W_bf16 [ND*KD] (2 MiB) | starts [NSEG+1]
  unsigned short* hb     = (unsigned short*)d_ws;
  unsigned short* Wb     = (unsigned short*)((char*)d_ws + (size_t)NSEG * KD * 2);
  int*            starts = (int*)((char*)d_ws + (size_t)NSEG * KD * 2 + (size_t)ND * KD * 2);

  prep_kernel<<<dim3(1024 + (NIDX + 256) / 256), 256, 0, stream>>>(W_dense, Wb, seg, starts);
  segmean_kernel<<<dim3(NSEG), 256, 0, stream>>>(hid, indices, starts, hb, out, b_proj);
  gemm_gelu_proj_kernel<<<dim3(NSEG / 128, ND / 128), 512, 0, stream>>>(hb, Wb, b_dense, W_proj, out);
}